// Round 2
// baseline (2012.495 us; speedup 1.0000x reference)
//
#include <hip/hip_runtime.h>

// DBRX block: B=4 S=1024 D=1024 H=16 KV=4 HD=64 E=8 F=4096 topK=2
// Attention path in split-bf16 (fp32-accurate) so router top-2 matches the
// fp32 reference; MoE path in plain bf16 MFMA. ~400MB workspace.

typedef float f32x4 __attribute__((ext_vector_type(4)));
typedef __bf16 bf16x8 __attribute__((ext_vector_type(8)));

static __device__ __forceinline__ unsigned short f2bf(float f) {
  unsigned int x = __float_as_uint(f);
  unsigned int r = x + 0x7fffu + ((x >> 16) & 1u);
  return (unsigned short)(r >> 16);
}
static __device__ __forceinline__ float bf2f(unsigned short u) {
  return __uint_as_float(((unsigned int)u) << 16);
}

// ---------------- elementwise cast fp32 -> bf16 ----------------
__global__ __launch_bounds__(256) void k_cast(const float* __restrict__ in,
                                              unsigned short* __restrict__ out, int n) {
  int i = (blockIdx.x * 256 + threadIdx.x) * 4;
  if (i >= n) return;
  float4 v = *(const float4*)(in + i);
  unsigned short o[4] __attribute__((aligned(8)));
  o[0] = f2bf(v.x); o[1] = f2bf(v.y); o[2] = f2bf(v.z); o[3] = f2bf(v.w);
  *(uint2*)(out + i) = *(uint2*)o;
}

// ---------------- transpose + cast: in [R][C] fp32 -> out [C][R] bf16 ----------------
__global__ void k_transpose_cast(const float* __restrict__ in, unsigned short* __restrict__ out,
                                 int R, int C) {
  __shared__ float t[32][33];
  long zo = (long)blockIdx.z * R * C;
  int c0 = blockIdx.x * 32, r0 = blockIdx.y * 32;
  int tx = threadIdx.x, ty = threadIdx.y;
#pragma unroll
  for (int i = 0; i < 4; ++i) {
    int r = r0 + ty + i * 8;
    t[ty + i * 8][tx] = in[zo + (long)r * C + c0 + tx];
  }
  __syncthreads();
#pragma unroll
  for (int i = 0; i < 4; ++i) {
    int c = c0 + ty + i * 8;
    out[zo + (long)c * R + r0 + tx] = f2bf(t[tx][ty + i * 8]);
  }
}

// ---------------- transpose + SPLIT cast: fp32 -> bf16 hi + bf16 lo ----------------
__global__ void k_transpose_cast_split(const float* __restrict__ in,
                                       unsigned short* __restrict__ oh,
                                       unsigned short* __restrict__ ol, int R, int C) {
  __shared__ float t[32][33];
  int c0 = blockIdx.x * 32, r0 = blockIdx.y * 32;
  int tx = threadIdx.x, ty = threadIdx.y;
#pragma unroll
  for (int i = 0; i < 4; ++i) {
    int r = r0 + ty + i * 8;
    t[ty + i * 8][tx] = in[(long)r * C + c0 + tx];
  }
  __syncthreads();
#pragma unroll
  for (int i = 0; i < 4; ++i) {
    float v = t[tx][ty + i * 8];
    unsigned short h = f2bf(v);
    long o = (long)(c0 + ty + i * 8) * R + r0 + tx;
    oh[o] = h;
    ol[o] = f2bf(v - bf2f(h));
  }
}

// ---------------- LayerNorm 1: fp32 in -> split bf16 (hi+lo) out ----------------
__global__ __launch_bounds__(256) void k_ln1(const float* __restrict__ x,
                                             const float* __restrict__ scale,
                                             unsigned short* __restrict__ oh,
                                             unsigned short* __restrict__ ol) {
  int row = blockIdx.x, tid = threadIdx.x;
  float4 v = ((const float4*)(x + (long)row * 1024))[tid];
  float s = v.x + v.y + v.z + v.w;
  float q = v.x * v.x + v.y * v.y + v.z * v.z + v.w * v.w;
#pragma unroll
  for (int off = 1; off < 64; off <<= 1) { s += __shfl_xor(s, off, 64); q += __shfl_xor(q, off, 64); }
  __shared__ float rs_[4], rq_[4];
  int w = tid >> 6;
  if ((tid & 63) == 0) { rs_[w] = s; rq_[w] = q; }
  __syncthreads();
  s = rs_[0] + rs_[1] + rs_[2] + rs_[3];
  q = rq_[0] + rq_[1] + rq_[2] + rq_[3];
  float mu = s * (1.f / 1024.f);
  float var = q * (1.f / 1024.f) - mu * mu;
  float rstd = rsqrtf(var + 1e-5f);
  float4 sc = ((const float4*)scale)[tid];
  float y[4] = {(v.x - mu) * rstd * sc.x, (v.y - mu) * rstd * sc.y,
                (v.z - mu) * rstd * sc.z, (v.w - mu) * rstd * sc.w};
  unsigned short ohv[4] __attribute__((aligned(8)));
  unsigned short olv[4] __attribute__((aligned(8)));
#pragma unroll
  for (int i = 0; i < 4; ++i) {
    unsigned short h = f2bf(y[i]);
    ohv[i] = h;
    olv[i] = f2bf(y[i] - bf2f(h));
  }
  *(uint2*)(oh + (long)row * 1024 + tid * 4) = *(uint2*)ohv;
  *(uint2*)(ol + (long)row * 1024 + tid * 4) = *(uint2*)olv;
}

// ---------------- LayerNorm 2: residual -> h2 bf16 + h2 fp32 + d_out=residual ----------------
__global__ __launch_bounds__(256) void k_ln2(const float* __restrict__ res,
                                             const float* __restrict__ scale,
                                             unsigned short* __restrict__ h2b,
                                             float* __restrict__ h2f,
                                             float* __restrict__ dout) {
  int row = blockIdx.x, tid = threadIdx.x;
  float4 v = ((const float4*)(res + (long)row * 1024))[tid];
  ((float4*)(dout + (long)row * 1024))[tid] = v;  // init output with residual
  float s = v.x + v.y + v.z + v.w;
  float q = v.x * v.x + v.y * v.y + v.z * v.z + v.w * v.w;
#pragma unroll
  for (int off = 1; off < 64; off <<= 1) { s += __shfl_xor(s, off, 64); q += __shfl_xor(q, off, 64); }
  __shared__ float rs_[4], rq_[4];
  int w = tid >> 6;
  if ((tid & 63) == 0) { rs_[w] = s; rq_[w] = q; }
  __syncthreads();
  s = rs_[0] + rs_[1] + rs_[2] + rs_[3];
  q = rq_[0] + rq_[1] + rq_[2] + rq_[3];
  float mu = s * (1.f / 1024.f);
  float var = q * (1.f / 1024.f) - mu * mu;
  float rstd = rsqrtf(var + 1e-5f);
  float4 sc = ((const float4*)scale)[tid];
  float4 nv;
  nv.x = (v.x - mu) * rstd * sc.x;
  nv.y = (v.y - mu) * rstd * sc.y;
  nv.z = (v.z - mu) * rstd * sc.z;
  nv.w = (v.w - mu) * rstd * sc.w;
  ((float4*)(h2f + (long)row * 1024))[tid] = nv;
  unsigned short o[4] __attribute__((aligned(8)));
  o[0] = f2bf(nv.x); o[1] = f2bf(nv.y); o[2] = f2bf(nv.z); o[3] = f2bf(nv.w);
  *(uint2*)(h2b + (long)row * 1024 + tid * 4) = *(uint2*)o;
}

// ---------------- MFMA GEMM core ----------------
typedef __bf16 ldsrow_t[72];  // BK=64 + pad 8 -> 2-way bank conflicts only (free)

static __device__ __forceinline__ void stage_tile(const unsigned short* __restrict__ src, long ld,
                                                  int k0, ldsrow_t* dst, int tid) {
  int row = tid >> 1, c = (tid & 1) * 32;
  const uint4* s = (const uint4*)(src + (long)row * ld + k0 + c);
  uint4 v0 = s[0], v1 = s[1], v2 = s[2], v3 = s[3];
  uint4* d = (uint4*)&dst[row][c];
  d[0] = v0; d[1] = v1; d[2] = v2; d[3] = v3;
}

static __device__ void mfma_loop(const unsigned short* __restrict__ A, long lda,
                                 const unsigned short* __restrict__ B, long ldb, int K,
                                 ldsrow_t* As, ldsrow_t* Bs, f32x4 acc[4][4]) {
  const int tid = threadIdx.x;
  const int lane = tid & 63;
  const int wm = tid >> 7, wn = (tid >> 6) & 1;
  const int lr = lane & 15, lq = lane >> 4;
  for (int k0 = 0; k0 < K; k0 += 64) {
    __syncthreads();
    stage_tile(A, lda, k0, As, tid);
    stage_tile(B, ldb, k0, Bs, tid);
    __syncthreads();
#pragma unroll
    for (int kk = 0; kk < 64; kk += 32) {
      bf16x8 af[4], bfr[4];
#pragma unroll
      for (int mt = 0; mt < 4; ++mt) af[mt] = *(const bf16x8*)&As[wm * 64 + mt * 16 + lr][kk + lq * 8];
#pragma unroll
      for (int nt = 0; nt < 4; ++nt) bfr[nt] = *(const bf16x8*)&Bs[wn * 64 + nt * 16 + lr][kk + lq * 8];
#pragma unroll
      for (int mt = 0; mt < 4; ++mt)
#pragma unroll
        for (int nt = 0; nt < 4; ++nt)
          acc[mt][nt] = __builtin_amdgcn_mfma_f32_16x16x32_bf16(af[mt], bfr[nt], acc[mt][nt], 0, 0, 0);
    }
  }
}

// Split-precision GEMM over K=1024: C = Ah*Bh + Ah*Bl + Al*Bh as one virtual
// K=3072 GEMM: [Ah|Ah|Al] . [Bh|Bl|Bh]. Same LDS footprint as mfma_loop.
static __device__ void mfma_loop_split(const unsigned short* __restrict__ Ah,
                                       const unsigned short* __restrict__ Al, long lda,
                                       const unsigned short* __restrict__ Bh,
                                       const unsigned short* __restrict__ Bl, long ldb,
                                       ldsrow_t* As, ldsrow_t* Bs, f32x4 acc[4][4]) {
  const int tid = threadIdx.x;
  const int lane = tid & 63;
  const int wm = tid >> 7, wn = (tid >> 6) & 1;
  const int lr = lane & 15, lq = lane >> 4;
  for (int kv = 0; kv < 3072; kv += 64) {
    int part = kv >> 10, k0 = kv & 1023;
    const unsigned short* A = (part < 2) ? Ah : Al;
    const unsigned short* B = (part == 1) ? Bl : Bh;
    __syncthreads();
    stage_tile(A, lda, k0, As, tid);
    stage_tile(B, ldb, k0, Bs, tid);
    __syncthreads();
#pragma unroll
    for (int kk = 0; kk < 64; kk += 32) {
      bf16x8 af[4], bfr[4];
#pragma unroll
      for (int mt = 0; mt < 4; ++mt) af[mt] = *(const bf16x8*)&As[wm * 64 + mt * 16 + lr][kk + lq * 8];
#pragma unroll
      for (int nt = 0; nt < 4; ++nt) bfr[nt] = *(const bf16x8*)&Bs[wn * 64 + nt * 16 + lr][kk + lq * 8];
#pragma unroll
      for (int mt = 0; mt < 4; ++mt)
#pragma unroll
        for (int nt = 0; nt < 4; ++nt)
          acc[mt][nt] = __builtin_amdgcn_mfma_f32_16x16x32_bf16(af[mt], bfr[nt], acc[mt][nt], 0, 0, 0);
    }
  }
}

static __device__ void mfma_loop2(const unsigned short* __restrict__ A, long lda,
                                  const unsigned short* __restrict__ B1,
                                  const unsigned short* __restrict__ B2, long ldb, int K,
                                  ldsrow_t* As, ldsrow_t* Bs1, ldsrow_t* Bs2,
                                  f32x4 acc1[4][4], f32x4 acc2[4][4]) {
  const int tid = threadIdx.x;
  const int lane = tid & 63;
  const int wm = tid >> 7, wn = (tid >> 6) & 1;
  const int lr = lane & 15, lq = lane >> 4;
  for (int k0 = 0; k0 < K; k0 += 64) {
    __syncthreads();
    stage_tile(A, lda, k0, As, tid);
    stage_tile(B1, ldb, k0, Bs1, tid);
    stage_tile(B2, ldb, k0, Bs2, tid);
    __syncthreads();
#pragma unroll
    for (int kk = 0; kk < 64; kk += 32) {
      bf16x8 af[4], b1f[4], b2f[4];
#pragma unroll
      for (int mt = 0; mt < 4; ++mt) af[mt] = *(const bf16x8*)&As[wm * 64 + mt * 16 + lr][kk + lq * 8];
#pragma unroll
      for (int nt = 0; nt < 4; ++nt) {
        b1f[nt] = *(const bf16x8*)&Bs1[wn * 64 + nt * 16 + lr][kk + lq * 8];
        b2f[nt] = *(const bf16x8*)&Bs2[wn * 64 + nt * 16 + lr][kk + lq * 8];
      }
#pragma unroll
      for (int mt = 0; mt < 4; ++mt)
#pragma unroll
        for (int nt = 0; nt < 4; ++nt) {
          acc1[mt][nt] = __builtin_amdgcn_mfma_f32_16x16x32_bf16(af[mt], b1f[nt], acc1[mt][nt], 0, 0, 0);
          acc2[mt][nt] = __builtin_amdgcn_mfma_f32_16x16x32_bf16(af[mt], b2f[nt], acc2[mt][nt], 0, 0, 0);
        }
    }
  }
}

#define ZERO_ACC(a)                          \
  _Pragma("unroll") for (int i_ = 0; i_ < 4; ++i_) \
  _Pragma("unroll") for (int j_ = 0; j_ < 4; ++j_) a[i_][j_] = (f32x4){0.f, 0.f, 0.f, 0.f};

// ---------------- GEMM: qkv = h1 @ wqkv  (split precision, fp32 out) ----------------
__global__ __launch_bounds__(256) void k_gemm_qkv(const unsigned short* __restrict__ h1h,
                                                  const unsigned short* __restrict__ h1l,
                                                  const unsigned short* __restrict__ wTh,
                                                  const unsigned short* __restrict__ wTl,
                                                  float* __restrict__ qkv) {
  __shared__ __align__(16) __bf16 As[128][72];
  __shared__ __align__(16) __bf16 Bs[128][72];
  f32x4 acc[4][4]; ZERO_ACC(acc);
  int m0 = blockIdx.y * 128, n0 = blockIdx.x * 128;
  mfma_loop_split(h1h + (long)m0 * 1024, h1l + (long)m0 * 1024, 1024,
                  wTh + (long)n0 * 1024, wTl + (long)n0 * 1024, 1024,
                  (ldsrow_t*)As, (ldsrow_t*)Bs, acc);
  const int lane = threadIdx.x & 63;
  const int wm = threadIdx.x >> 7, wn = (threadIdx.x >> 6) & 1;
  const int lr = lane & 15, lq = lane >> 4;
#pragma unroll
  for (int mt = 0; mt < 4; ++mt)
#pragma unroll
    for (int r = 0; r < 4; ++r) {
      int row = m0 + wm * 64 + mt * 16 + lq * 4 + r;
#pragma unroll
      for (int nt = 0; nt < 4; ++nt)
        qkv[(long)row * 1536 + n0 + wn * 64 + nt * 16 + lr] = acc[mt][nt][r];
    }
}

// ---------------- GEMM: residual = hs + attn_o @ out_proj (split precision) ----------------
__global__ __launch_bounds__(256) void k_gemm_proj(const unsigned short* __restrict__ aoh,
                                                   const unsigned short* __restrict__ aol,
                                                   const unsigned short* __restrict__ opTh,
                                                   const unsigned short* __restrict__ opTl,
                                                   const float* __restrict__ hs,
                                                   float* __restrict__ res) {
  __shared__ __align__(16) __bf16 As[128][72];
  __shared__ __align__(16) __bf16 Bs[128][72];
  f32x4 acc[4][4]; ZERO_ACC(acc);
  int m0 = blockIdx.y * 128, n0 = blockIdx.x * 128;
  mfma_loop_split(aoh + (long)m0 * 1024, aol + (long)m0 * 1024, 1024,
                  opTh + (long)n0 * 1024, opTl + (long)n0 * 1024, 1024,
                  (ldsrow_t*)As, (ldsrow_t*)Bs, acc);
  const int lane = threadIdx.x & 63;
  const int wm = threadIdx.x >> 7, wn = (threadIdx.x >> 6) & 1;
  const int lr = lane & 15, lq = lane >> 4;
#pragma unroll
  for (int mt = 0; mt < 4; ++mt)
#pragma unroll
    for (int r = 0; r < 4; ++r) {
      long row = m0 + wm * 64 + mt * 16 + lq * 4 + r;
#pragma unroll
      for (int nt = 0; nt < 4; ++nt) {
        long idx = row * 1024 + n0 + wn * 64 + nt * 16 + lr;
        res[idx] = hs[idx] + acc[mt][nt][r];
      }
    }
}

// ---------------- MoE GEMM1: x1 = silu(Xg@W1^T) * (Xg@V1^T)  bf16 out ----------------
__global__ __launch_bounds__(256) void k_gemm_moe1(const unsigned short* __restrict__ Xg,
                                                   const unsigned short* __restrict__ w1b,
                                                   const unsigned short* __restrict__ v1b,
                                                   const int* __restrict__ meta,
                                                   unsigned short* __restrict__ x1) {
  int slot = blockIdx.y;
  if (slot >= meta[24]) return;
  int e = meta[32 + slot], row0 = meta[104 + slot];
  int n0 = blockIdx.x * 128;
  __shared__ __align__(16) __bf16 As[128][72];
  __shared__ __align__(16) __bf16 Bs1[128][72];
  __shared__ __align__(16) __bf16 Bs2[128][72];
  f32x4 a1[4][4], a2[4][4]; ZERO_ACC(a1); ZERO_ACC(a2);
  mfma_loop2(Xg + (long)row0 * 1024, 1024,
             w1b + (long)e * 4194304 + (long)n0 * 1024,
             v1b + (long)e * 4194304 + (long)n0 * 1024, 1024, 1024,
             (ldsrow_t*)As, (ldsrow_t*)Bs1, (ldsrow_t*)Bs2, a1, a2);
  const int lane = threadIdx.x & 63;
  const int wm = threadIdx.x >> 7, wn = (threadIdx.x >> 6) & 1;
  const int lr = lane & 15, lq = lane >> 4;
#pragma unroll
  for (int mt = 0; mt < 4; ++mt)
#pragma unroll
    for (int r = 0; r < 4; ++r) {
      long row = row0 + wm * 64 + mt * 16 + lq * 4 + r;
#pragma unroll
      for (int nt = 0; nt < 4; ++nt) {
        float g = a1[mt][nt][r];
        float val = g / (1.f + __expf(-g)) * a2[mt][nt][r];
        x1[row * 4096 + n0 + wn * 64 + nt * 16 + lr] = f2bf(val);
      }
    }
}

// ---------------- MoE GEMM2: out += gate * (x1 @ W2)  via atomics ----------------
__global__ __launch_bounds__(256) void k_gemm_moe2(const unsigned short* __restrict__ x1,
                                                   const unsigned short* __restrict__ w2T,
                                                   const int* __restrict__ meta,
                                                   const int* __restrict__ pair_tok,
                                                   const float* __restrict__ pair_gate,
                                                   float* __restrict__ out) {
  int slot = blockIdx.y;
  if (slot >= meta[24]) return;
  int e = meta[32 + slot], row0 = meta[104 + slot];
  int n0 = blockIdx.x * 128;
  __shared__ __align__(16) __bf16 As[128][72];
  __shared__ __align__(16) __bf16 Bs[128][72];
  f32x4 acc[4][4]; ZERO_ACC(acc);
  mfma_loop(x1 + (long)row0 * 4096, 4096,
            w2T + (long)e * 4194304 + (long)n0 * 4096, 4096, 4096,
            (ldsrow_t*)As, (ldsrow_t*)Bs, acc);
  const int lane = threadIdx.x & 63;
  const int wm = threadIdx.x >> 7, wn = (threadIdx.x >> 6) & 1;
  const int lr = lane & 15, lq = lane >> 4;
#pragma unroll
  for (int mt = 0; mt < 4; ++mt)
#pragma unroll
    for (int r = 0; r < 4; ++r) {
      int grow = row0 + wm * 64 + mt * 16 + lq * 4 + r;
      int tok = pair_tok[grow];
      if (tok >= 0) {
        float g = pair_gate[grow];
#pragma unroll
        for (int nt = 0; nt < 4; ++nt)
          atomicAdd(&out[(long)tok * 1024 + n0 + wn * 64 + nt * 16 + lr], g * acc[mt][nt][r]);
      }
    }
}

// ---------------- RoPE + split/transpose qkv -> q/k/v fp32 ----------------
__global__ __launch_bounds__(256) void k_rope(const float* __restrict__ qkv,
                                              const int* __restrict__ posid,
                                              const float* __restrict__ rsin,
                                              const float* __restrict__ rcos,
                                              float* __restrict__ qf,
                                              float* __restrict__ kf,
                                              float* __restrict__ vf) {
  int bs = blockIdx.x;
  int b = bs >> 10, sidx = bs & 1023;
  int pos = posid[bs];
  const float* row = qkv + (long)bs * 1536;
  const float* cp = rcos + (long)pos * 64;
  const float* sp = rsin + (long)pos * 64;
  int tid = threadIdx.x;
  for (int i = tid; i < 640; i += 256) {  // (16 q heads + 4 k heads) * 32 pairs
    int hd = i >> 5, d = i & 31;
    float c = cp[d], sn = sp[d];
    if (hd < 16) {
      float x1 = row[hd * 64 + d], x2 = row[hd * 64 + d + 32];
      long o = (((long)(b * 16 + hd)) * 1024 + sidx) * 64;
      qf[o + d] = x1 * c - x2 * sn;
      qf[o + d + 32] = x2 * c + x1 * sn;
    } else {
      int kh = hd - 16;
      float x1 = row[1024 + kh * 64 + d], x2 = row[1024 + kh * 64 + d + 32];
      long o = (((long)(b * 4 + kh)) * 1024 + sidx) * 64;
      kf[o + d] = x1 * c - x2 * sn;
      kf[o + d + 32] = x2 * c + x1 * sn;
    }
  }
  {
    int vh = tid >> 6, d = tid & 63;  // 256 v elems, 256 threads
    vf[(((long)(b * 4 + vh)) * 1024 + sidx) * 64 + d] = row[1280 + tid];
  }
}

// ---------------- flash attention (causal, GQA), fp32, 16 q-rows per block ----------------
__global__ __launch_bounds__(256) void k_attn(const float* __restrict__ qb,
                                              const float* __restrict__ kb,
                                              const float* __restrict__ vb,
                                              unsigned short* __restrict__ aoh,
                                              unsigned short* __restrict__ aol) {
  const int b = blockIdx.z, h = blockIdx.y, q0 = blockIdx.x * 16;
  const int kvh = h >> 2;
  __shared__ float Kt[64][65], Vt[64][65], Ql[16][64], Pb[4][64];
  const int tid = threadIdx.x, lane = tid & 63, w = tid >> 6;
  const long qbase = (((long)(b * 16 + h)) * 1024 + q0) * 64;
  for (int i = tid; i < 1024; i += 256) {
    int r = i >> 6, d = i & 63;
    Ql[r][d] = qb[qbase + r * 64 + d] * 0.125f;  // fold 1/sqrt(64)
  }
  float m[4], l[4], o[4];
#pragma unroll
  for (int i = 0; i < 4; ++i) { m[i] = -3.0e38f; l[i] = 0.f; o[i] = 0.f; }
  const int ntiles = (q0 >> 6) + 1;
  const long kvbase = ((long)(b * 4 + kvh)) * 1024 * 64;
  for (int t = 0; t < ntiles; ++t) {
    __syncthreads();
    int j0 = t * 64;
    for (int i = tid; i < 4096; i += 256) {
      int r = i >> 6, d = i & 63;
      Kt[r][d] = kb[kvbase + (long)(j0 + r) * 64 + d];
      Vt[r][d] = vb[kvbase + (long)(j0 + r) * 64 + d];
    }
    __syncthreads();
#pragma unroll
    for (int i = 0; i < 4; ++i) {
      int rq = q0 + w * 4 + i;
      float dot = 0.f;
#pragma unroll
      for (int d = 0; d < 64; ++d) dot += Ql[w * 4 + i][d] * Kt[lane][d];
      float s = (j0 + lane <= rq) ? dot : -1e30f;
      float mt_ = s;
#pragma unroll
      for (int off = 1; off < 64; off <<= 1) mt_ = fmaxf(mt_, __shfl_xor(mt_, off, 64));
      float mnew = fmaxf(m[i], mt_);
      float p = __expf(s - mnew);
      float alpha = __expf(m[i] - mnew);
      float ps = p;
#pragma unroll
      for (int off = 1; off < 64; off <<= 1) ps += __shfl_xor(ps, off, 64);
      l[i] = l[i] * alpha + ps;
      m[i] = mnew;
      asm volatile("s_waitcnt lgkmcnt(0)" ::: "memory");  // prior Pb reads done (WAR)
      Pb[w][lane] = p;
      asm volatile("s_waitcnt lgkmcnt(0)" ::: "memory");  // Pb write visible to wave
      float accv = 0.f;
#pragma unroll
      for (int j = 0; j < 64; ++j) accv += Pb[w][j] * Vt[j][lane];
      o[i] = o[i] * alpha + accv;
    }
  }
  const long obase = ((long)(b * 1024 + q0)) * 1024 + h * 64;
#pragma unroll
  for (int i = 0; i < 4; ++i) {
    float val = o[i] / l[i];
    unsigned short hh = f2bf(val);
    long idx = obase + (long)(w * 4 + i) * 1024 + lane;
    aoh[idx] = hh;
    aol[idx] = f2bf(val - bf2f(hh));
  }
}

// ---------------- router: fp32 logits, top-2, renormalize ----------------
__global__ __launch_bounds__(256) void k_router(const float* __restrict__ h2f,
                                                const float* __restrict__ rw,
                                                int* __restrict__ top_e,
                                                float* __restrict__ top_w) {
  int w = threadIdx.x >> 6, lane = threadIdx.x & 63;
  int token = blockIdx.x * 4 + w;
  float acc[8] = {0.f, 0.f, 0.f, 0.f, 0.f, 0.f, 0.f, 0.f};
  const float* x = h2f + (long)token * 1024;
  for (int d = lane; d < 1024; d += 64) {
    float xv = x[d];
    float4 r0 = *(const float4*)(rw + d * 8);
    float4 r1 = *(const float4*)(rw + d * 8 + 4);
    acc[0] += xv * r0.x; acc[1] += xv * r0.y; acc[2] += xv * r0.z; acc[3] += xv * r0.w;
    acc[4] += xv * r1.x; acc[5] += xv * r1.y; acc[6] += xv * r1.z; acc[7] += xv * r1.w;
  }
#pragma unroll
  for (int e = 0; e < 8; ++e)
#pragma unroll
    for (int off = 1; off < 64; off <<= 1) acc[e] += __shfl_xor(acc[e], off, 64);
  if (lane == 0) {
    int e0 = 0; float l0 = acc[0];
#pragma unroll
    for (int e = 1; e < 8; ++e) if (acc[e] > l0) { l0 = acc[e]; e0 = e; }
    int e1 = (e0 == 0) ? 1 : 0; float l1 = acc[e1];
#pragma unroll
    for (int e = 0; e < 8; ++e) if (e != e0 && acc[e] > l1) { l1 = acc[e]; e1 = e; }
    float w0 = 1.f / (1.f + __expf(l1 - l0));
    top_e[token * 2] = e0; top_e[token * 2 + 1] = e1;
    top_w[token * 2] = w0; top_w[token * 2 + 1] = 1.f - w0;
  }
}

// ---------------- MoE prep: counts, segment bases, tile table ----------------
__global__ __launch_bounds__(256) void k_moe_prep(const int* __restrict__ top_e,
                                                  int* __restrict__ meta,
                                                  int* __restrict__ pair_tok) {
  __shared__ int cnt[8];
  int tid = threadIdx.x;
  if (tid < 8) cnt[tid] = 0;
  for (int i = tid; i < 9216; i += 256) pair_tok[i] = -1;
  __syncthreads();
  for (int i = tid; i < 8192; i += 256) atomicAdd(&cnt[top_e[i]], 1);
  __syncthreads();
  if (tid == 0) {
    int base = 0, nt = 0;
    for (int e = 0; e < 8; ++e) {
      int c = cnt[e];
      meta[e] = c; meta[8 + e] = base; meta[16 + e] = base;  // count, base, cursor
      int t = (c + 127) >> 7;
      for (int i = 0; i < t; ++i) { meta[32 + nt] = e; meta[104 + nt] = base + (i << 7); ++nt; }
      base += (t << 7);
    }
    meta[24] = nt;
  }
}

__global__ __launch_bounds__(256) void k_pair_fill(const int* __restrict__ top_e,
                                                   const float* __restrict__ top_w,
                                                   int* __restrict__ meta,
                                                   int* __restrict__ pair_tok,
                                                   float* __restrict__ pair_gate) {
  int token = blockIdx.x * 256 + threadIdx.x;
  if (token >= 4096) return;
  for (int k = 0; k < 2; ++k) {
    int e = top_e[token * 2 + k];
    int pos = atomicAdd(&meta[16 + e], 1);
    pair_tok[pos] = token;
    pair_gate[pos] = top_w[token * 2 + k];
  }
}

__global__ __launch_bounds__(256) void k_gather(const int* __restrict__ pair_tok,
                                                const unsigned short* __restrict__ h2b,
                                                unsigned short* __restrict__ Xg) {
  int rowi = blockIdx.x;
  int tok = pair_tok[rowi];
  uint2* dst = (uint2*)(Xg + (long)rowi * 1024);
  if (tok >= 0) {
    const uint2* src = (const uint2*)(h2b + (long)tok * 1024);
    dst[threadIdx.x] = src[threadIdx.x];
  } else {
    dst[threadIdx.x] = make_uint2(0u, 0u);
  }
}

// ---------------- launch ----------------
extern "C" void kernel_launch(void* const* d_in, const int* in_sizes, int n_in,
                              void* d_out, int out_size, void* d_ws, size_t ws_size,
                              hipStream_t stream) {
  const float* hs    = (const float*)d_in[0];
  const int*   posid = (const int*)d_in[1];
  const float* ln1s  = (const float*)d_in[2];
  const float* ln2s  = (const float*)d_in[3];
  const float* wqkv  = (const float*)d_in[4];
  const float* oproj = (const float*)d_in[5];
  const float* rw    = (const float*)d_in[6];
  const float* w1    = (const float*)d_in[7];
  const float* v1    = (const float*)d_in[8];
  const float* w2    = (const float*)d_in[9];
  const float* rsin  = (const float*)d_in[10];
  const float* rcos  = (const float*)d_in[11];
  float* out = (float*)d_out;

  char* ws = (char*)d_ws;
  size_t off = 0;
  auto alloc = [&](size_t b) { char* p = ws + off; off = (off + b + 255) & ~(size_t)255; return p; };
  unsigned short* w1b    = (unsigned short*)alloc(8ul * 4096 * 1024 * 2);
  unsigned short* v1b    = (unsigned short*)alloc(8ul * 4096 * 1024 * 2);
  unsigned short* w2T    = (unsigned short*)alloc(8ul * 4096 * 1024 * 2);
  unsigned short* wqkvTh = (unsigned short*)alloc(1536ul * 1024 * 2);
  unsigned short* wqkvTl = (unsigned short*)alloc(1536ul * 1024 * 2);
  unsigned short* opTh   = (unsigned short*)alloc(1024ul * 1024 * 2);
  unsigned short* opTl   = (unsigned short*)alloc(1024ul * 1024 * 2);
  // region A: h1 split (hi+lo), later reused for residual (h1 dead after qkv GEMM)
  char* regA = alloc(4096ul * 1024 * 4);
  unsigned short* h1h = (unsigned short*)regA;
  unsigned short* h1l = h1h + 4096ul * 1024;
  float*          res = (float*)regA;
  // region B: qkv fp32, later reused for ao split (qkv dead after rope)
  char* regB = alloc(4096ul * 1536 * 4);
  float*          qkvb = (float*)regB;
  unsigned short* aoh  = (unsigned short*)regB;
  unsigned short* aol  = aoh + 4096ul * 1024;
  // region C: q fp32, later reused for h2 fp32 (q dead after attention)
  char* regC = alloc(4ul * 16 * 1024 * 64 * 4);
  float* qf  = (float*)regC;
  float* h2f = (float*)regC;
  float*          kf    = (float*)alloc(4ul * 4 * 1024 * 64 * 4);
  float*          vf    = (float*)alloc(4ul * 4 * 1024 * 64 * 4);
  unsigned short* h2b   = (unsigned short*)alloc(4096ul * 1024 * 2);
  int*            tope  = (int*)alloc(8192ul * 4);
  float*          topw  = (float*)alloc(8192ul * 4);
  int*            ptok  = (int*)alloc(9216ul * 4);
  float*          pgate = (float*)alloc(9216ul * 4);
  unsigned short* Xg    = (unsigned short*)alloc(9216ul * 1024 * 2);
  unsigned short* x1    = (unsigned short*)alloc(9216ul * 4096 * 2);
  int*            meta  = (int*)alloc(1024);
  (void)ws_size; (void)in_sizes; (void)n_in; (void)out_size;

  // weight conversions
  k_cast<<<dim3(32768), dim3(256), 0, stream>>>(w1, w1b, 33554432);
  k_cast<<<dim3(32768), dim3(256), 0, stream>>>(v1, v1b, 33554432);
  k_transpose_cast<<<dim3(32, 128, 8), dim3(32, 8), 0, stream>>>(w2, w2T, 4096, 1024);
  k_transpose_cast_split<<<dim3(48, 32), dim3(32, 8), 0, stream>>>(wqkv, wqkvTh, wqkvTl, 1024, 1536);
  k_transpose_cast_split<<<dim3(32, 32), dim3(32, 8), 0, stream>>>(oproj, opTh, opTl, 1024, 1024);
  // attention path (split precision -> fp32-accurate residual)
  k_ln1<<<dim3(4096), dim3(256), 0, stream>>>(hs, ln1s, h1h, h1l);
  k_gemm_qkv<<<dim3(12, 32), dim3(256), 0, stream>>>(h1h, h1l, wqkvTh, wqkvTl, qkvb);
  k_rope<<<dim3(4096), dim3(256), 0, stream>>>(qkvb, posid, rsin, rcos, qf, kf, vf);
  k_attn<<<dim3(64, 16, 4), dim3(256), 0, stream>>>(qf, kf, vf, aoh, aol);
  k_gemm_proj<<<dim3(8, 32), dim3(256), 0, stream>>>(aoh, aol, opTh, opTl, hs, res);
  // MoE path
  k_ln2<<<dim3(4096), dim3(256), 0, stream>>>(res, ln2s, h2b, h2f, out);
  k_router<<<dim3(1024), dim3(256), 0, stream>>>(h2f, rw, tope, topw);
  k_moe_prep<<<dim3(1), dim3(256), 0, stream>>>(tope, meta, ptok);
  k_pair_fill<<<dim3(16), dim3(256), 0, stream>>>(tope, topw, meta, ptok, pgate);
  k_gather<<<dim3(9216), dim3(256), 0, stream>>>(ptok, h2b, Xg);
  k_gemm_moe1<<<dim3(32, 72), dim3(256), 0, stream>>>(Xg, w1b, v1b, meta, x1);
  k_gemm_moe2<<<dim3(8, 72), dim3(256), 0, stream>>>(x1, w2T, meta, ptok, pgate, out);
}

// Round 3
// 1258.235 us; speedup vs baseline: 1.5995x; 1.5995x over previous
//
#include <hip/hip_runtime.h>

// DBRX block: B=4 S=1024 D=1024 H=16 KV=4 HD=64 E=8 F=4096 topK=2
// Attention path in split-bf16 (fp32-accurate) so router top-2 matches the
// fp32 reference; MoE path in plain bf16 MFMA. ~400MB workspace.
// R3: attention rewritten as split-bf16 MFMA flash attention (was VALU/LDS-bound).

typedef float f32x4 __attribute__((ext_vector_type(4)));
typedef __bf16 bf16x8 __attribute__((ext_vector_type(8)));

static __device__ __forceinline__ unsigned short f2bf(float f) {
  unsigned int x = __float_as_uint(f);
  unsigned int r = x + 0x7fffu + ((x >> 16) & 1u);
  return (unsigned short)(r >> 16);
}
static __device__ __forceinline__ float bf2f(unsigned short u) {
  return __uint_as_float(((unsigned int)u) << 16);
}

// split 8 fp32 (two f32x4) into hi/lo bf16x8 fragments
static __device__ __forceinline__ void split8(f32x4 a, f32x4 b, bf16x8& hi, bf16x8& lo) {
#pragma unroll
  for (int j = 0; j < 4; ++j) {
    __bf16 h = (__bf16)a[j];
    hi[j] = h;
    lo[j] = (__bf16)(a[j] - (float)h);
  }
#pragma unroll
  for (int j = 0; j < 4; ++j) {
    __bf16 h = (__bf16)b[j];
    hi[4 + j] = h;
    lo[4 + j] = (__bf16)(b[j] - (float)h);
  }
}

// ---------------- elementwise cast fp32 -> bf16 ----------------
__global__ __launch_bounds__(256) void k_cast(const float* __restrict__ in,
                                              unsigned short* __restrict__ out, int n) {
  int i = (blockIdx.x * 256 + threadIdx.x) * 4;
  if (i >= n) return;
  float4 v = *(const float4*)(in + i);
  unsigned short o[4] __attribute__((aligned(8)));
  o[0] = f2bf(v.x); o[1] = f2bf(v.y); o[2] = f2bf(v.z); o[3] = f2bf(v.w);
  *(uint2*)(out + i) = *(uint2*)o;
}

// ---------------- transpose + cast: in [R][C] fp32 -> out [C][R] bf16 ----------------
__global__ void k_transpose_cast(const float* __restrict__ in, unsigned short* __restrict__ out,
                                 int R, int C) {
  __shared__ float t[32][33];
  long zo = (long)blockIdx.z * R * C;
  int c0 = blockIdx.x * 32, r0 = blockIdx.y * 32;
  int tx = threadIdx.x, ty = threadIdx.y;
#pragma unroll
  for (int i = 0; i < 4; ++i) {
    int r = r0 + ty + i * 8;
    t[ty + i * 8][tx] = in[zo + (long)r * C + c0 + tx];
  }
  __syncthreads();
#pragma unroll
  for (int i = 0; i < 4; ++i) {
    int c = c0 + ty + i * 8;
    out[zo + (long)c * R + r0 + tx] = f2bf(t[tx][ty + i * 8]);
  }
}

// ---------------- transpose + SPLIT cast: fp32 -> bf16 hi + bf16 lo ----------------
__global__ void k_transpose_cast_split(const float* __restrict__ in,
                                       unsigned short* __restrict__ oh,
                                       unsigned short* __restrict__ ol, int R, int C) {
  __shared__ float t[32][33];
  int c0 = blockIdx.x * 32, r0 = blockIdx.y * 32;
  int tx = threadIdx.x, ty = threadIdx.y;
#pragma unroll
  for (int i = 0; i < 4; ++i) {
    int r = r0 + ty + i * 8;
    t[ty + i * 8][tx] = in[(long)r * C + c0 + tx];
  }
  __syncthreads();
#pragma unroll
  for (int i = 0; i < 4; ++i) {
    float v = t[tx][ty + i * 8];
    unsigned short h = f2bf(v);
    long o = (long)(c0 + ty + i * 8) * R + r0 + tx;
    oh[o] = h;
    ol[o] = f2bf(v - bf2f(h));
  }
}

// ---------------- LayerNorm 1: fp32 in -> split bf16 (hi+lo) out ----------------
__global__ __launch_bounds__(256) void k_ln1(const float* __restrict__ x,
                                             const float* __restrict__ scale,
                                             unsigned short* __restrict__ oh,
                                             unsigned short* __restrict__ ol) {
  int row = blockIdx.x, tid = threadIdx.x;
  float4 v = ((const float4*)(x + (long)row * 1024))[tid];
  float s = v.x + v.y + v.z + v.w;
  float q = v.x * v.x + v.y * v.y + v.z * v.z + v.w * v.w;
#pragma unroll
  for (int off = 1; off < 64; off <<= 1) { s += __shfl_xor(s, off, 64); q += __shfl_xor(q, off, 64); }
  __shared__ float rs_[4], rq_[4];
  int w = tid >> 6;
  if ((tid & 63) == 0) { rs_[w] = s; rq_[w] = q; }
  __syncthreads();
  s = rs_[0] + rs_[1] + rs_[2] + rs_[3];
  q = rq_[0] + rq_[1] + rq_[2] + rq_[3];
  float mu = s * (1.f / 1024.f);
  float var = q * (1.f / 1024.f) - mu * mu;
  float rstd = rsqrtf(var + 1e-5f);
  float4 sc = ((const float4*)scale)[tid];
  float y[4] = {(v.x - mu) * rstd * sc.x, (v.y - mu) * rstd * sc.y,
                (v.z - mu) * rstd * sc.z, (v.w - mu) * rstd * sc.w};
  unsigned short ohv[4] __attribute__((aligned(8)));
  unsigned short olv[4] __attribute__((aligned(8)));
#pragma unroll
  for (int i = 0; i < 4; ++i) {
    unsigned short h = f2bf(y[i]);
    ohv[i] = h;
    olv[i] = f2bf(y[i] - bf2f(h));
  }
  *(uint2*)(oh + (long)row * 1024 + tid * 4) = *(uint2*)ohv;
  *(uint2*)(ol + (long)row * 1024 + tid * 4) = *(uint2*)olv;
}

// ---------------- LayerNorm 2: residual -> h2 bf16 + h2 fp32 + d_out=residual ----------------
__global__ __launch_bounds__(256) void k_ln2(const float* __restrict__ res,
                                             const float* __restrict__ scale,
                                             unsigned short* __restrict__ h2b,
                                             float* __restrict__ h2f,
                                             float* __restrict__ dout) {
  int row = blockIdx.x, tid = threadIdx.x;
  float4 v = ((const float4*)(res + (long)row * 1024))[tid];
  ((float4*)(dout + (long)row * 1024))[tid] = v;  // init output with residual
  float s = v.x + v.y + v.z + v.w;
  float q = v.x * v.x + v.y * v.y + v.z * v.z + v.w * v.w;
#pragma unroll
  for (int off = 1; off < 64; off <<= 1) { s += __shfl_xor(s, off, 64); q += __shfl_xor(q, off, 64); }
  __shared__ float rs_[4], rq_[4];
  int w = tid >> 6;
  if ((tid & 63) == 0) { rs_[w] = s; rq_[w] = q; }
  __syncthreads();
  s = rs_[0] + rs_[1] + rs_[2] + rs_[3];
  q = rq_[0] + rq_[1] + rq_[2] + rq_[3];
  float mu = s * (1.f / 1024.f);
  float var = q * (1.f / 1024.f) - mu * mu;
  float rstd = rsqrtf(var + 1e-5f);
  float4 sc = ((const float4*)scale)[tid];
  float4 nv;
  nv.x = (v.x - mu) * rstd * sc.x;
  nv.y = (v.y - mu) * rstd * sc.y;
  nv.z = (v.z - mu) * rstd * sc.z;
  nv.w = (v.w - mu) * rstd * sc.w;
  ((float4*)(h2f + (long)row * 1024))[tid] = nv;
  unsigned short o[4] __attribute__((aligned(8)));
  o[0] = f2bf(nv.x); o[1] = f2bf(nv.y); o[2] = f2bf(nv.z); o[3] = f2bf(nv.w);
  *(uint2*)(h2b + (long)row * 1024 + tid * 4) = *(uint2*)o;
}

// ---------------- MFMA GEMM core ----------------
typedef __bf16 ldsrow_t[72];  // BK=64 + pad 8 -> 2-way bank conflicts only (free)

static __device__ __forceinline__ void stage_tile(const unsigned short* __restrict__ src, long ld,
                                                  int k0, ldsrow_t* dst, int tid) {
  int row = tid >> 1, c = (tid & 1) * 32;
  const uint4* s = (const uint4*)(src + (long)row * ld + k0 + c);
  uint4 v0 = s[0], v1 = s[1], v2 = s[2], v3 = s[3];
  uint4* d = (uint4*)&dst[row][c];
  d[0] = v0; d[1] = v1; d[2] = v2; d[3] = v3;
}

static __device__ void mfma_loop(const unsigned short* __restrict__ A, long lda,
                                 const unsigned short* __restrict__ B, long ldb, int K,
                                 ldsrow_t* As, ldsrow_t* Bs, f32x4 acc[4][4]) {
  const int tid = threadIdx.x;
  const int lane = tid & 63;
  const int wm = tid >> 7, wn = (tid >> 6) & 1;
  const int lr = lane & 15, lq = lane >> 4;
  for (int k0 = 0; k0 < K; k0 += 64) {
    __syncthreads();
    stage_tile(A, lda, k0, As, tid);
    stage_tile(B, ldb, k0, Bs, tid);
    __syncthreads();
#pragma unroll
    for (int kk = 0; kk < 64; kk += 32) {
      bf16x8 af[4], bfr[4];
#pragma unroll
      for (int mt = 0; mt < 4; ++mt) af[mt] = *(const bf16x8*)&As[wm * 64 + mt * 16 + lr][kk + lq * 8];
#pragma unroll
      for (int nt = 0; nt < 4; ++nt) bfr[nt] = *(const bf16x8*)&Bs[wn * 64 + nt * 16 + lr][kk + lq * 8];
#pragma unroll
      for (int mt = 0; mt < 4; ++mt)
#pragma unroll
        for (int nt = 0; nt < 4; ++nt)
          acc[mt][nt] = __builtin_amdgcn_mfma_f32_16x16x32_bf16(af[mt], bfr[nt], acc[mt][nt], 0, 0, 0);
    }
  }
}

// Split-precision GEMM over K=1024: C = Ah*Bh + Ah*Bl + Al*Bh as one virtual
// K=3072 GEMM: [Ah|Ah|Al] . [Bh|Bl|Bh]. Same LDS footprint as mfma_loop.
static __device__ void mfma_loop_split(const unsigned short* __restrict__ Ah,
                                       const unsigned short* __restrict__ Al, long lda,
                                       const unsigned short* __restrict__ Bh,
                                       const unsigned short* __restrict__ Bl, long ldb,
                                       ldsrow_t* As, ldsrow_t* Bs, f32x4 acc[4][4]) {
  const int tid = threadIdx.x;
  const int lane = tid & 63;
  const int wm = tid >> 7, wn = (tid >> 6) & 1;
  const int lr = lane & 15, lq = lane >> 4;
  for (int kv = 0; kv < 3072; kv += 64) {
    int part = kv >> 10, k0 = kv & 1023;
    const unsigned short* A = (part < 2) ? Ah : Al;
    const unsigned short* B = (part == 1) ? Bl : Bh;
    __syncthreads();
    stage_tile(A, lda, k0, As, tid);
    stage_tile(B, ldb, k0, Bs, tid);
    __syncthreads();
#pragma unroll
    for (int kk = 0; kk < 64; kk += 32) {
      bf16x8 af[4], bfr[4];
#pragma unroll
      for (int mt = 0; mt < 4; ++mt) af[mt] = *(const bf16x8*)&As[wm * 64 + mt * 16 + lr][kk + lq * 8];
#pragma unroll
      for (int nt = 0; nt < 4; ++nt) bfr[nt] = *(const bf16x8*)&Bs[wn * 64 + nt * 16 + lr][kk + lq * 8];
#pragma unroll
      for (int mt = 0; mt < 4; ++mt)
#pragma unroll
        for (int nt = 0; nt < 4; ++nt)
          acc[mt][nt] = __builtin_amdgcn_mfma_f32_16x16x32_bf16(af[mt], bfr[nt], acc[mt][nt], 0, 0, 0);
    }
  }
}

static __device__ void mfma_loop2(const unsigned short* __restrict__ A, long lda,
                                  const unsigned short* __restrict__ B1,
                                  const unsigned short* __restrict__ B2, long ldb, int K,
                                  ldsrow_t* As, ldsrow_t* Bs1, ldsrow_t* Bs2,
                                  f32x4 acc1[4][4], f32x4 acc2[4][4]) {
  const int tid = threadIdx.x;
  const int lane = tid & 63;
  const int wm = tid >> 7, wn = (tid >> 6) & 1;
  const int lr = lane & 15, lq = lane >> 4;
  for (int k0 = 0; k0 < K; k0 += 64) {
    __syncthreads();
    stage_tile(A, lda, k0, As, tid);
    stage_tile(B1, ldb, k0, Bs1, tid);
    stage_tile(B2, ldb, k0, Bs2, tid);
    __syncthreads();
#pragma unroll
    for (int kk = 0; kk < 64; kk += 32) {
      bf16x8 af[4], b1f[4], b2f[4];
#pragma unroll
      for (int mt = 0; mt < 4; ++mt) af[mt] = *(const bf16x8*)&As[wm * 64 + mt * 16 + lr][kk + lq * 8];
#pragma unroll
      for (int nt = 0; nt < 4; ++nt) {
        b1f[nt] = *(const bf16x8*)&Bs1[wn * 64 + nt * 16 + lr][kk + lq * 8];
        b2f[nt] = *(const bf16x8*)&Bs2[wn * 64 + nt * 16 + lr][kk + lq * 8];
      }
#pragma unroll
      for (int mt = 0; mt < 4; ++mt)
#pragma unroll
        for (int nt = 0; nt < 4; ++nt) {
          acc1[mt][nt] = __builtin_amdgcn_mfma_f32_16x16x32_bf16(af[mt], b1f[nt], acc1[mt][nt], 0, 0, 0);
          acc2[mt][nt] = __builtin_amdgcn_mfma_f32_16x16x32_bf16(af[mt], b2f[nt], acc2[mt][nt], 0, 0, 0);
        }
    }
  }
}

#define ZERO_ACC(a)                          \
  _Pragma("unroll") for (int i_ = 0; i_ < 4; ++i_) \
  _Pragma("unroll") for (int j_ = 0; j_ < 4; ++j_) a[i_][j_] = (f32x4){0.f, 0.f, 0.f, 0.f};

// ---------------- GEMM: qkv = h1 @ wqkv  (split precision, fp32 out) ----------------
__global__ __launch_bounds__(256) void k_gemm_qkv(const unsigned short* __restrict__ h1h,
                                                  const unsigned short* __restrict__ h1l,
                                                  const unsigned short* __restrict__ wTh,
                                                  const unsigned short* __restrict__ wTl,
                                                  float* __restrict__ qkv) {
  __shared__ __align__(16) __bf16 As[128][72];
  __shared__ __align__(16) __bf16 Bs[128][72];
  f32x4 acc[4][4]; ZERO_ACC(acc);
  int m0 = blockIdx.y * 128, n0 = blockIdx.x * 128;
  mfma_loop_split(h1h + (long)m0 * 1024, h1l + (long)m0 * 1024, 1024,
                  wTh + (long)n0 * 1024, wTl + (long)n0 * 1024, 1024,
                  (ldsrow_t*)As, (ldsrow_t*)Bs, acc);
  const int lane = threadIdx.x & 63;
  const int wm = threadIdx.x >> 7, wn = (threadIdx.x >> 6) & 1;
  const int lr = lane & 15, lq = lane >> 4;
#pragma unroll
  for (int mt = 0; mt < 4; ++mt)
#pragma unroll
    for (int r = 0; r < 4; ++r) {
      int row = m0 + wm * 64 + mt * 16 + lq * 4 + r;
#pragma unroll
      for (int nt = 0; nt < 4; ++nt)
        qkv[(long)row * 1536 + n0 + wn * 64 + nt * 16 + lr] = acc[mt][nt][r];
    }
}

// ---------------- GEMM: residual = hs + attn_o @ out_proj (split precision) ----------------
__global__ __launch_bounds__(256) void k_gemm_proj(const unsigned short* __restrict__ aoh,
                                                   const unsigned short* __restrict__ aol,
                                                   const unsigned short* __restrict__ opTh,
                                                   const unsigned short* __restrict__ opTl,
                                                   const float* __restrict__ hs,
                                                   float* __restrict__ res) {
  __shared__ __align__(16) __bf16 As[128][72];
  __shared__ __align__(16) __bf16 Bs[128][72];
  f32x4 acc[4][4]; ZERO_ACC(acc);
  int m0 = blockIdx.y * 128, n0 = blockIdx.x * 128;
  mfma_loop_split(aoh + (long)m0 * 1024, aol + (long)m0 * 1024, 1024,
                  opTh + (long)n0 * 1024, opTl + (long)n0 * 1024, 1024,
                  (ldsrow_t*)As, (ldsrow_t*)Bs, acc);
  const int lane = threadIdx.x & 63;
  const int wm = threadIdx.x >> 7, wn = (threadIdx.x >> 6) & 1;
  const int lr = lane & 15, lq = lane >> 4;
#pragma unroll
  for (int mt = 0; mt < 4; ++mt)
#pragma unroll
    for (int r = 0; r < 4; ++r) {
      long row = m0 + wm * 64 + mt * 16 + lq * 4 + r;
#pragma unroll
      for (int nt = 0; nt < 4; ++nt) {
        long idx = row * 1024 + n0 + wn * 64 + nt * 16 + lr;
        res[idx] = hs[idx] + acc[mt][nt][r];
      }
    }
}

// ---------------- MoE GEMM1: x1 = silu(Xg@W1^T) * (Xg@V1^T)  bf16 out ----------------
__global__ __launch_bounds__(256) void k_gemm_moe1(const unsigned short* __restrict__ Xg,
                                                   const unsigned short* __restrict__ w1b,
                                                   const unsigned short* __restrict__ v1b,
                                                   const int* __restrict__ meta,
                                                   unsigned short* __restrict__ x1) {
  int slot = blockIdx.y;
  if (slot >= meta[24]) return;
  int e = meta[32 + slot], row0 = meta[104 + slot];
  int n0 = blockIdx.x * 128;
  __shared__ __align__(16) __bf16 As[128][72];
  __shared__ __align__(16) __bf16 Bs1[128][72];
  __shared__ __align__(16) __bf16 Bs2[128][72];
  f32x4 a1[4][4], a2[4][4]; ZERO_ACC(a1); ZERO_ACC(a2);
  mfma_loop2(Xg + (long)row0 * 1024, 1024,
             w1b + (long)e * 4194304 + (long)n0 * 1024,
             v1b + (long)e * 4194304 + (long)n0 * 1024, 1024, 1024,
             (ldsrow_t*)As, (ldsrow_t*)Bs1, (ldsrow_t*)Bs2, a1, a2);
  const int lane = threadIdx.x & 63;
  const int wm = threadIdx.x >> 7, wn = (threadIdx.x >> 6) & 1;
  const int lr = lane & 15, lq = lane >> 4;
#pragma unroll
  for (int mt = 0; mt < 4; ++mt)
#pragma unroll
    for (int r = 0; r < 4; ++r) {
      long row = row0 + wm * 64 + mt * 16 + lq * 4 + r;
#pragma unroll
      for (int nt = 0; nt < 4; ++nt) {
        float g = a1[mt][nt][r];
        float val = g / (1.f + __expf(-g)) * a2[mt][nt][r];
        x1[row * 4096 + n0 + wn * 64 + nt * 16 + lr] = f2bf(val);
      }
    }
}

// ---------------- MoE GEMM2: out += gate * (x1 @ W2)  via atomics ----------------
__global__ __launch_bounds__(256) void k_gemm_moe2(const unsigned short* __restrict__ x1,
                                                   const unsigned short* __restrict__ w2T,
                                                   const int* __restrict__ meta,
                                                   const int* __restrict__ pair_tok,
                                                   const float* __restrict__ pair_gate,
                                                   float* __restrict__ out) {
  int slot = blockIdx.y;
  if (slot >= meta[24]) return;
  int e = meta[32 + slot], row0 = meta[104 + slot];
  int n0 = blockIdx.x * 128;
  __shared__ __align__(16) __bf16 As[128][72];
  __shared__ __align__(16) __bf16 Bs[128][72];
  f32x4 acc[4][4]; ZERO_ACC(acc);
  mfma_loop(x1 + (long)row0 * 4096, 4096,
            w2T + (long)e * 4194304 + (long)n0 * 4096, 4096, 4096,
            (ldsrow_t*)As, (ldsrow_t*)Bs, acc);
  const int lane = threadIdx.x & 63;
  const int wm = threadIdx.x >> 7, wn = (threadIdx.x >> 6) & 1;
  const int lr = lane & 15, lq = lane >> 4;
#pragma unroll
  for (int mt = 0; mt < 4; ++mt)
#pragma unroll
    for (int r = 0; r < 4; ++r) {
      int grow = row0 + wm * 64 + mt * 16 + lq * 4 + r;
      int tok = pair_tok[grow];
      if (tok >= 0) {
        float g = pair_gate[grow];
#pragma unroll
        for (int nt = 0; nt < 4; ++nt)
          atomicAdd(&out[(long)tok * 1024 + n0 + wn * 64 + nt * 16 + lr], g * acc[mt][nt][r]);
      }
    }
}

// ---------------- RoPE + split/transpose qkv -> q/k fp32, v^T fp32 ----------------
__global__ __launch_bounds__(256) void k_rope(const float* __restrict__ qkv,
                                              const int* __restrict__ posid,
                                              const float* __restrict__ rsin,
                                              const float* __restrict__ rcos,
                                              float* __restrict__ qf,
                                              float* __restrict__ kf,
                                              float* __restrict__ vtf) {
  int bs = blockIdx.x;
  int b = bs >> 10, sidx = bs & 1023;
  int pos = posid[bs];
  const float* row = qkv + (long)bs * 1536;
  const float* cp = rcos + (long)pos * 64;
  const float* sp = rsin + (long)pos * 64;
  int tid = threadIdx.x;
  for (int i = tid; i < 640; i += 256) {  // (16 q heads + 4 k heads) * 32 pairs
    int hd = i >> 5, d = i & 31;
    float c = cp[d], sn = sp[d];
    if (hd < 16) {
      float x1 = row[hd * 64 + d], x2 = row[hd * 64 + d + 32];
      long o = (((long)(b * 16 + hd)) * 1024 + sidx) * 64;
      qf[o + d] = x1 * c - x2 * sn;
      qf[o + d + 32] = x2 * c + x1 * sn;
    } else {
      int kh = hd - 16;
      float x1 = row[1024 + kh * 64 + d], x2 = row[1024 + kh * 64 + d + 32];
      long o = (((long)(b * 4 + kh)) * 1024 + sidx) * 64;
      kf[o + d] = x1 * c - x2 * sn;
      kf[o + d + 32] = x2 * c + x1 * sn;
    }
  }
  {
    int vh = tid >> 6, d = tid & 63;  // V transposed: [b][kvh][hd][seq]
    vtf[(((long)(b * 4 + vh)) * 64 + d) * 1024 + sidx] = row[1280 + tid];
  }
}

// ---------------- MFMA flash attention (causal, GQA), split-bf16, 64 q-rows/block ----------------
// Per wave: 16 q-rows. QK^T and PV as 3-term split-bf16 MFMA (error ~2^-16).
__global__ __launch_bounds__(256) void k_attn(const float* __restrict__ qf,
                                              const float* __restrict__ kf,
                                              const float* __restrict__ vtf,
                                              unsigned short* __restrict__ aoh,
                                              unsigned short* __restrict__ aol) {
  const int b = blockIdx.z, h = blockIdx.y, qt = blockIdx.x;
  const int kvh = h >> 2;
  __shared__ __align__(16) float Ks[64][68];      // [key][hd]
  __shared__ __align__(16) float Vt[64][68];      // [hd][key]
  __shared__ __align__(16) float Pw[4][16][68];   // per-wave P round-trip
  const int tid = threadIdx.x, lane = tid & 63, w = tid >> 6;
  const int quad = lane >> 4, l15 = lane & 15;

  // Q fragments (A-operand layout: m=l15, k=quad*8+j), scaled by 1/sqrt(64)
  const int qrow_a = qt * 64 + w * 16 + l15;
  const float* qptr = qf + (((long)(b * 16 + h)) * 1024 + qrow_a) * 64;
  bf16x8 qh[2], ql[2];
#pragma unroll
  for (int kc = 0; kc < 2; ++kc) {
    f32x4 a, c;
#pragma unroll
    for (int j = 0; j < 4; ++j) a[j] = qptr[kc * 32 + quad * 8 + j] * 0.125f;
#pragma unroll
    for (int j = 0; j < 4; ++j) c[j] = qptr[kc * 32 + quad * 8 + 4 + j] * 0.125f;
    split8(a, c, qh[kc], ql[kc]);
  }

  f32x4 O[4];
#pragma unroll
  for (int i = 0; i < 4; ++i) O[i] = (f32x4){0.f, 0.f, 0.f, 0.f};
  float m_i[4], l_i[4];
#pragma unroll
  for (int i = 0; i < 4; ++i) { m_i[i] = -3.0e38f; l_i[i] = 0.f; }

  const long kvbase = ((long)(b * 4 + kvh)) * 65536;  // 1024*64
  const int ntiles = qt + 1;
  for (int t = 0; t < ntiles; ++t) {
    const int j0 = t * 64;
    __syncthreads();
    // stage K [key][hd] and V^T [hd][key] — both coalesced global, conflict-free LDS
    for (int i = tid; i < 4096; i += 256) {
      int r = i >> 6, d = i & 63;
      Ks[r][d] = kf[kvbase + (long)(j0 + r) * 64 + d];
      Vt[r][d] = vtf[kvbase + (long)r * 1024 + j0 + d];
    }
    __syncthreads();
    // S = Q K^T (3-term split)
    f32x4 S[4];
#pragma unroll
    for (int i = 0; i < 4; ++i) S[i] = (f32x4){0.f, 0.f, 0.f, 0.f};
#pragma unroll
    for (int kc = 0; kc < 2; ++kc) {
#pragma unroll
      for (int nt = 0; nt < 4; ++nt) {
        const float* kp = &Ks[nt * 16 + l15][kc * 32 + quad * 8];
        f32x4 x = *(const f32x4*)kp, y = *(const f32x4*)(kp + 4);
        bf16x8 kh, kl;
        split8(x, y, kh, kl);
        S[nt] = __builtin_amdgcn_mfma_f32_16x16x32_bf16(qh[kc], kh, S[nt], 0, 0, 0);
        S[nt] = __builtin_amdgcn_mfma_f32_16x16x32_bf16(qh[kc], kl, S[nt], 0, 0, 0);
        S[nt] = __builtin_amdgcn_mfma_f32_16x16x32_bf16(ql[kc], kh, S[nt], 0, 0, 0);
      }
    }
    // causal mask (C layout: col=l15 within nt, row=quad*4+r)
#pragma unroll
    for (int nt = 0; nt < 4; ++nt) {
      int key = j0 + nt * 16 + l15;
#pragma unroll
      for (int r = 0; r < 4; ++r) {
        int qr = qt * 64 + w * 16 + quad * 4 + r;
        if (key > qr) S[nt][r] = -1.0e30f;
      }
    }
    // online softmax per row
#pragma unroll
    for (int r = 0; r < 4; ++r) {
      float mx = fmaxf(fmaxf(S[0][r], S[1][r]), fmaxf(S[2][r], S[3][r]));
#pragma unroll
      for (int off = 1; off < 16; off <<= 1) mx = fmaxf(mx, __shfl_xor(mx, off, 64));
      float mnew = fmaxf(m_i[r], mx);
      float alpha = __expf(m_i[r] - mnew);
      m_i[r] = mnew;
      float ps = 0.f;
#pragma unroll
      for (int nt = 0; nt < 4; ++nt) {
        float p = __expf(S[nt][r] - mnew);
        S[nt][r] = p;
        ps += p;
      }
#pragma unroll
      for (int off = 1; off < 16; off <<= 1) ps += __shfl_xor(ps, off, 64);
      l_i[r] = l_i[r] * alpha + ps;
#pragma unroll
      for (int nt = 0; nt < 4; ++nt) O[nt][r] *= alpha;
    }
    // P: C-layout -> LDS -> A-layout (per-wave buffer, wave-coherent via waitcnt)
    asm volatile("s_waitcnt lgkmcnt(0)" ::: "memory");  // prior Pw reads done (WAR)
#pragma unroll
    for (int nt = 0; nt < 4; ++nt)
#pragma unroll
      for (int r = 0; r < 4; ++r) Pw[w][quad * 4 + r][nt * 16 + l15] = S[nt][r];
    asm volatile("s_waitcnt lgkmcnt(0)" ::: "memory");  // Pw writes visible to wave
    // O += P V (3-term split)
#pragma unroll
    for (int kc2 = 0; kc2 < 2; ++kc2) {
      const float* pp = &Pw[w][l15][kc2 * 32 + quad * 8];
      f32x4 px = *(const f32x4*)pp, py = *(const f32x4*)(pp + 4);
      bf16x8 ph, pl;
      split8(px, py, ph, pl);
#pragma unroll
      for (int nt = 0; nt < 4; ++nt) {
        const float* vp = &Vt[nt * 16 + l15][kc2 * 32 + quad * 8];
        f32x4 vx = *(const f32x4*)vp, vy = *(const f32x4*)(vp + 4);
        bf16x8 vh, vl;
        split8(vx, vy, vh, vl);
        O[nt] = __builtin_amdgcn_mfma_f32_16x16x32_bf16(ph, vh, O[nt], 0, 0, 0);
        O[nt] = __builtin_amdgcn_mfma_f32_16x16x32_bf16(ph, vl, O[nt], 0, 0, 0);
        O[nt] = __builtin_amdgcn_mfma_f32_16x16x32_bf16(pl, vh, O[nt], 0, 0, 0);
      }
    }
  }
  // epilogue: ao[b, q, h*64+hd] split hi/lo
#pragma unroll
  for (int nt = 0; nt < 4; ++nt)
#pragma unroll
    for (int r = 0; r < 4; ++r) {
      float val = O[nt][r] / l_i[r];
      long q = qt * 64 + w * 16 + quad * 4 + r;
      long idx = ((long)b * 1024 + q) * 1024 + h * 64 + nt * 16 + l15;
      unsigned short hh = f2bf(val);
      aoh[idx] = hh;
      aol[idx] = f2bf(val - bf2f(hh));
    }
}

// ---------------- router: fp32 logits, top-2, renormalize ----------------
__global__ __launch_bounds__(256) void k_router(const float* __restrict__ h2f,
                                                const float* __restrict__ rw,
                                                int* __restrict__ top_e,
                                                float* __restrict__ top_w) {
  int w = threadIdx.x >> 6, lane = threadIdx.x & 63;
  int token = blockIdx.x * 4 + w;
  float acc[8] = {0.f, 0.f, 0.f, 0.f, 0.f, 0.f, 0.f, 0.f};
  const float* x = h2f + (long)token * 1024;
  for (int d = lane; d < 1024; d += 64) {
    float xv = x[d];
    float4 r0 = *(const float4*)(rw + d * 8);
    float4 r1 = *(const float4*)(rw + d * 8 + 4);
    acc[0] += xv * r0.x; acc[1] += xv * r0.y; acc[2] += xv * r0.z; acc[3] += xv * r0.w;
    acc[4] += xv * r1.x; acc[5] += xv * r1.y; acc[6] += xv * r1.z; acc[7] += xv * r1.w;
  }
#pragma unroll
  for (int e = 0; e < 8; ++e)
#pragma unroll
    for (int off = 1; off < 64; off <<= 1) acc[e] += __shfl_xor(acc[e], off, 64);
  if (lane == 0) {
    int e0 = 0; float l0 = acc[0];
#pragma unroll
    for (int e = 1; e < 8; ++e) if (acc[e] > l0) { l0 = acc[e]; e0 = e; }
    int e1 = (e0 == 0) ? 1 : 0; float l1 = acc[e1];
#pragma unroll
    for (int e = 0; e < 8; ++e) if (e != e0 && acc[e] > l1) { l1 = acc[e]; e1 = e; }
    float w0 = 1.f / (1.f + __expf(l1 - l0));
    top_e[token * 2] = e0; top_e[token * 2 + 1] = e1;
    top_w[token * 2] = w0; top_w[token * 2 + 1] = 1.f - w0;
  }
}

// ---------------- MoE prep: counts, segment bases, tile table ----------------
__global__ __launch_bounds__(256) void k_moe_prep(const int* __restrict__ top_e,
                                                  int* __restrict__ meta,
                                                  int* __restrict__ pair_tok) {
  __shared__ int cnt[8];
  int tid = threadIdx.x;
  if (tid < 8) cnt[tid] = 0;
  for (int i = tid; i < 9216; i += 256) pair_tok[i] = -1;
  __syncthreads();
  for (int i = tid; i < 8192; i += 256) atomicAdd(&cnt[top_e[i]], 1);
  __syncthreads();
  if (tid == 0) {
    int base = 0, nt = 0;
    for (int e = 0; e < 8; ++e) {
      int c = cnt[e];
      meta[e] = c; meta[8 + e] = base; meta[16 + e] = base;  // count, base, cursor
      int t = (c + 127) >> 7;
      for (int i = 0; i < t; ++i) { meta[32 + nt] = e; meta[104 + nt] = base + (i << 7); ++nt; }
      base += (t << 7);
    }
    meta[24] = nt;
  }
}

__global__ __launch_bounds__(256) void k_pair_fill(const int* __restrict__ top_e,
                                                   const float* __restrict__ top_w,
                                                   int* __restrict__ meta,
                                                   int* __restrict__ pair_tok,
                                                   float* __restrict__ pair_gate) {
  int token = blockIdx.x * 256 + threadIdx.x;
  if (token >= 4096) return;
  for (int k = 0; k < 2; ++k) {
    int e = top_e[token * 2 + k];
    int pos = atomicAdd(&meta[16 + e], 1);
    pair_tok[pos] = token;
    pair_gate[pos] = top_w[token * 2 + k];
  }
}

__global__ __launch_bounds__(256) void k_gather(const int* __restrict__ pair_tok,
                                                const unsigned short* __restrict__ h2b,
                                                unsigned short* __restrict__ Xg) {
  int rowi = blockIdx.x;
  int tok = pair_tok[rowi];
  uint2* dst = (uint2*)(Xg + (long)rowi * 1024);
  if (tok >= 0) {
    const uint2* src = (const uint2*)(h2b + (long)tok * 1024);
    dst[threadIdx.x] = src[threadIdx.x];
  } else {
    dst[threadIdx.x] = make_uint2(0u, 0u);
  }
}

// ---------------- launch ----------------
extern "C" void kernel_launch(void* const* d_in, const int* in_sizes, int n_in,
                              void* d_out, int out_size, void* d_ws, size_t ws_size,
                              hipStream_t stream) {
  const float* hs    = (const float*)d_in[0];
  const int*   posid = (const int*)d_in[1];
  const float* ln1s  = (const float*)d_in[2];
  const float* ln2s  = (const float*)d_in[3];
  const float* wqkv  = (const float*)d_in[4];
  const float* oproj = (const float*)d_in[5];
  const float* rw    = (const float*)d_in[6];
  const float* w1    = (const float*)d_in[7];
  const float* v1    = (const float*)d_in[8];
  const float* w2    = (const float*)d_in[9];
  const float* rsin  = (const float*)d_in[10];
  const float* rcos  = (const float*)d_in[11];
  float* out = (float*)d_out;

  char* ws = (char*)d_ws;
  size_t off = 0;
  auto alloc = [&](size_t b) { char* p = ws + off; off = (off + b + 255) & ~(size_t)255; return p; };
  unsigned short* w1b    = (unsigned short*)alloc(8ul * 4096 * 1024 * 2);
  unsigned short* v1b    = (unsigned short*)alloc(8ul * 4096 * 1024 * 2);
  unsigned short* w2T    = (unsigned short*)alloc(8ul * 4096 * 1024 * 2);
  unsigned short* wqkvTh = (unsigned short*)alloc(1536ul * 1024 * 2);
  unsigned short* wqkvTl = (unsigned short*)alloc(1536ul * 1024 * 2);
  unsigned short* opTh   = (unsigned short*)alloc(1024ul * 1024 * 2);
  unsigned short* opTl   = (unsigned short*)alloc(1024ul * 1024 * 2);
  // region A: h1 split (hi+lo), later reused for residual (h1 dead after qkv GEMM)
  char* regA = alloc(4096ul * 1024 * 4);
  unsigned short* h1h = (unsigned short*)regA;
  unsigned short* h1l = h1h + 4096ul * 1024;
  float*          res = (float*)regA;
  // region B: qkv fp32, later reused for ao split (qkv dead after rope)
  char* regB = alloc(4096ul * 1536 * 4);
  float*          qkvb = (float*)regB;
  unsigned short* aoh  = (unsigned short*)regB;
  unsigned short* aol  = aoh + 4096ul * 1024;
  // region C: q fp32, later reused for h2 fp32 (q dead after attention)
  char* regC = alloc(4ul * 16 * 1024 * 64 * 4);
  float* qf  = (float*)regC;
  float* h2f = (float*)regC;
  float*          kf    = (float*)alloc(4ul * 4 * 1024 * 64 * 4);
  float*          vtf   = (float*)alloc(4ul * 4 * 64 * 1024 * 4);
  unsigned short* h2b   = (unsigned short*)alloc(4096ul * 1024 * 2);
  int*            tope  = (int*)alloc(8192ul * 4);
  float*          topw  = (float*)alloc(8192ul * 4);
  int*            ptok  = (int*)alloc(9216ul * 4);
  float*          pgate = (float*)alloc(9216ul * 4);
  unsigned short* Xg    = (unsigned short*)alloc(9216ul * 1024 * 2);
  unsigned short* x1    = (unsigned short*)alloc(9216ul * 4096 * 2);
  int*            meta  = (int*)alloc(1024);
  (void)ws_size; (void)in_sizes; (void)n_in; (void)out_size;

  // weight conversions
  k_cast<<<dim3(32768), dim3(256), 0, stream>>>(w1, w1b, 33554432);
  k_cast<<<dim3(32768), dim3(256), 0, stream>>>(v1, v1b, 33554432);
  k_transpose_cast<<<dim3(32, 128, 8), dim3(32, 8), 0, stream>>>(w2, w2T, 4096, 1024);
  k_transpose_cast_split<<<dim3(48, 32), dim3(32, 8), 0, stream>>>(wqkv, wqkvTh, wqkvTl, 1024, 1536);
  k_transpose_cast_split<<<dim3(32, 32), dim3(32, 8), 0, stream>>>(oproj, opTh, opTl, 1024, 1024);
  // attention path (split precision -> fp32-accurate residual)
  k_ln1<<<dim3(4096), dim3(256), 0, stream>>>(hs, ln1s, h1h, h1l);
  k_gemm_qkv<<<dim3(12, 32), dim3(256), 0, stream>>>(h1h, h1l, wqkvTh, wqkvTl, qkvb);
  k_rope<<<dim3(4096), dim3(256), 0, stream>>>(qkvb, posid, rsin, rcos, qf, kf, vtf);
  k_attn<<<dim3(16, 16, 4), dim3(256), 0, stream>>>(qf, kf, vtf, aoh, aol);
  k_gemm_proj<<<dim3(8, 32), dim3(256), 0, stream>>>(aoh, aol, opTh, opTl, hs, res);
  // MoE path
  k_ln2<<<dim3(4096), dim3(256), 0, stream>>>(res, ln2s, h2b, h2f, out);
  k_router<<<dim3(1024), dim3(256), 0, stream>>>(h2f, rw, tope, topw);
  k_moe_prep<<<dim3(1), dim3(256), 0, stream>>>(tope, meta, ptok);
  k_pair_fill<<<dim3(16), dim3(256), 0, stream>>>(tope, topw, meta, ptok, pgate);
  k_gather<<<dim3(9216), dim3(256), 0, stream>>>(ptok, h2b, Xg);
  k_gemm_moe1<<<dim3(32, 72), dim3(256), 0, stream>>>(Xg, w1b, v1b, meta, x1);
  k_gemm_moe2<<<dim3(8, 72), dim3(256), 0, stream>>>(x1, w2T, meta, ptok, pgate, out);
}